// Round 16
// baseline (8688.445 us; speedup 1.0000x reference)
//
#include <hip/hip_runtime.h>
#include <hip/hip_bf16.h>

// LSTM: T=512, B=64, H=512, L=2.  inputs: x[T,B,H] f32, Wh[L,H,4H], Wx[L,H,4H], bh[L,4H]
// out = concat(out[T,B,H], h_fin[L,B,H], c_fin[L,B,H]) f32.
//
// R16: LAYER-FUSED persistent kernel. 64 WGs = 4 quads x 16 strips, 1024 thr.
// Stage s: L0@t=s (waves 0-7) and L1@t=s-1 (waves 8-15) in ONE WG.
// L0 needs xq[s] (cached) + h0[s-1]; L1 needs h0[s-1] (SAME tile, loaded
// once) + h1[s-2]. Tagged 8B records (R13-proven: [2 bf16 | tag=t+1], relaxed
// sc1, data IS the flag, serialized per-pair retries). vs R13: half the
// spinning WGs, 3MB->2MB/stage coherent reads, no kh partial-sum, no
// throttle flag (stage-s entry proves peers reached s-1; clobber dist 8).
// Staging is whole-WG (R9's failure was splitting STAGING across waves;
// here only COMPUTE is wave-split). All barriers unconditional.

#define TSEQ 512
#define BATCH 64
#define HID 512
#define H4 2048
#define BH (BATCH * HID)
#define DEPTH 8
#define QR 16            // batch rows per quad
#define RPR 256          // records per row (HID/2)
#define BRPR (BATCH * RPR)

typedef short bf16x8 __attribute__((ext_vector_type(8)));
typedef float f32x4 __attribute__((ext_vector_type(4)));
typedef float f32x2 __attribute__((ext_vector_type(2)));
typedef unsigned long long u64;
typedef u64 u64x2 __attribute__((ext_vector_type(2)));

__device__ __forceinline__ ushort f32_to_bf16(float f) {
    unsigned u = __builtin_bit_cast(unsigned, f);
    u += 0x7FFFu + ((u >> 16) & 1u);   // round-to-nearest-even
    return (ushort)(u >> 16);
}

// retry-load 4 tagged records (32B) until all tags == tag; returns 8 bf16
__device__ __forceinline__ bf16x8 load_tagged(const u64* p, unsigned tag) {
    u64x2 a, b;
    for (;;) {
        asm volatile("global_load_dwordx4 %0, %2, off sc1\n\t"
                     "global_load_dwordx4 %1, %3, off sc1\n\t"
                     "s_waitcnt vmcnt(0)"
                     : "=&v"(a), "=&v"(b) : "v"(p), "v"(p + 2) : "memory");
        if ((unsigned)(a.x >> 32) == tag && (unsigned)(a.y >> 32) == tag &&
            (unsigned)(b.x >> 32) == tag && (unsigned)(b.y >> 32) == tag) break;
        __builtin_amdgcn_s_sleep(1);
    }
    union { unsigned u[4]; bf16x8 v; } r;
    r.u[0] = (unsigned)a.x; r.u[1] = (unsigned)a.y;
    r.u[2] = (unsigned)b.x; r.u[3] = (unsigned)b.y;
    return r.v;
}

// ---- convert x f32 -> bf16 (vectorized) ----
__global__ __launch_bounds__(256) void convert_x(const float* __restrict__ x,
                                                 ushort* __restrict__ xq) {
    const int n4 = (TSEQ * BATCH * HID) / 4;
    int stride = gridDim.x * blockDim.x;
    for (int i = blockIdx.x * blockDim.x + threadIdx.x; i < n4; i += stride) {
        float4 v = ((const float4*)x)[i];
        ushort4 o;
        o.x = f32_to_bf16(v.x);
        o.y = f32_to_bf16(v.y);
        o.z = f32_to_bf16(v.z);
        o.w = f32_to_bf16(v.w);
        ((ushort4*)xq)[i] = o;
    }
}

// ---- transpose+convert weights: WT[m][n][k] = W[k][n], m: 0=Wx0 1=Wh0 2=Wx1 3=Wh1 ----
__global__ __launch_bounds__(256) void transpose_w(const float* __restrict__ Wh,
                                                   const float* __restrict__ Wx,
                                                   ushort* __restrict__ WT) {
    int bid = blockIdx.x;            // 4 * 8 * 32 = 1024 blocks
    int m  = bid >> 8;               // 0..3
    int kt = (bid >> 5) & 7;         // k tile (64)
    int nt = bid & 31;               // n tile (64)
    const float* src = ((m & 1) ? Wh : Wx) + (size_t)(m >> 1) * (HID * H4);

    __shared__ float tile[64][65];
    int c  = threadIdx.x & 63;
    int r0 = (threadIdx.x >> 6) * 16;
    for (int i = 0; i < 16; ++i) {
        int r = r0 + i;
        tile[r][c] = src[(size_t)(kt * 64 + r) * H4 + nt * 64 + c];
    }
    __syncthreads();
    int k  = threadIdx.x & 63;
    int n0 = (threadIdx.x >> 6) * 16;
    for (int i = 0; i < 16; ++i) {
        int n = n0 + i;
        WT[(size_t)m * (H4 * HID) + (size_t)(nt * 64 + n) * HID + kt * 64 + k] =
            f32_to_bf16(tile[k][n]);
    }
}

// ---- persistent LSTM kernel: 64 WGs x 1024 threads, both layers fused ----
__global__ __launch_bounds__(1024, 1) void lstm_persistent(
    const ushort* __restrict__ WT,   // [4][2048][512] bf16 (N-major, K contiguous)
    const ushort* __restrict__ xq,   // [512][64][512] bf16
    const float*  __restrict__ bh,   // [2][2048]
    u64*   __restrict__ h0T,         // [DEPTH][64][256] tagged records
    u64*   __restrict__ h1T,         // [DEPTH][64][256]
    float* __restrict__ out)         // d_out
{
    const int wg    = blockIdx.x;        // 0..63
    const int quad  = wg >> 4;
    const int strip = wg & 15;           // 32-column strip
    const int j0    = strip * 32;
    const int tid   = threadIdx.x;
    const int wave  = tid >> 6;          // 0..15
    const int lane  = tid & 63;
    const int lgrp  = wave >> 3;         // 0 = L0 waves, 1 = L1 waves
    const int lw    = wave & 7;
    const int g     = lw & 3;            // gate
    const int ch    = lw >> 2;           // col-tile half (16 cols)
    const int lo    = lane & 15;
    const int hi    = lane >> 4;

    // weight fragment base pointers for THIS wave's layer (gemm_bt layout)
    const ushort* bxp = WT + (size_t)(lgrp * 2 + 0) * (H4 * HID)
                      + (size_t)(g * 512 + j0 + ch * 16 + lo) * HID + hi * 8;
    const ushort* bwp = WT + (size_t)(lgrp * 2 + 1) * (H4 * HID)
                      + (size_t)(g * 512 + j0 + ch * 16 + lo) * HID + hi * 8;

    // gate-phase mapping: threads 0..255 -> L0, 256..511 -> L1
    const int glayer = tid >> 8;                  // valid for tid < 512
    const int gtid   = tid & 255;
    const int grow   = gtid >> 4;                 // 0..15
    const int cp     = (gtid & 15) * 2;           // 0..30
    f32x2 bias2[4];
#pragma unroll
    for (int gg = 0; gg < 4; ++gg)
        bias2[gg] = *(const f32x2*)&bh[(glayer & 1) * H4 + gg * 512 + j0 + cp];
    f32x2 creg = (f32x2)(0.f);

    __shared__ __align__(16) ushort ldsX[QR * HID];        // 16 KB xq tile
    __shared__ __align__(16) ushort ldsA0[QR * HID];       // 16 KB h0[s-1]
    __shared__ __align__(16) ushort ldsA1[QR * HID];       // 16 KB h1[s-2]
    __shared__ __align__(16) float  lds_g[2][4][QR][34];   // final gates, padded

    // staging: 1024 threads, 8 bf16 (4 records) per tile
    const int row  = tid >> 6;             // 0..15
    const int kba  = tid & 63;
    const int goff  = (quad * QR + row) * HID + kba * 8;               // bf16 elems
    const int roff  = (quad * QR + row) * RPR + kba * 4;               // records
    const int laddr = ((row << 10) + (kba << 4)) ^ ((row & 15) << 4);
    const bf16x8 zero8 = {0, 0, 0, 0, 0, 0, 0, 0};

    for (int s = 0; s <= TSEQ; ++s) {
        const int t0 = s;                  // L0 timestep
        const int t1 = s - 1;              // L1 timestep
        const bool act0 = (t0 < TSEQ);
        const bool act1 = (t1 >= 0);

        // ---- acquire (whole WG) ----
        bf16x8 vX = act0 ? *(const bf16x8*)(xq + (size_t)t0 * BH + goff) : zero8;
        bf16x8 v0 = (s >= 1)
            ? load_tagged(h0T + (size_t)((s - 1) & 7) * BRPR + roff, (unsigned)s)
            : zero8;                       // h0[s-1], tag s (serves L0-self + L1-cross)
        bf16x8 v1 = (s >= 2)
            ? load_tagged(h1T + (size_t)((s - 2) & 7) * BRPR + roff, (unsigned)(s - 1))
            : zero8;                       // h1[s-2], tag s-1
        __builtin_amdgcn_sched_barrier(0);
        *(bf16x8*)((char*)ldsX  + laddr) = vX;
        *(bf16x8*)((char*)ldsA0 + laddr) = v0;
        *(bf16x8*)((char*)ldsA1 + laddr) = v1;
        __syncthreads();                   // bar1: tiles staged

        // ---- MFMA: wave-split by layer; full K per wave (32 MFMAs) ----
        const bool wact = lgrp ? act1 : act0;
        if (wact) {
            const char* a1base = lgrp ? (const char*)ldsA0 : (const char*)ldsX;
            const char* a2base = lgrp ? (const char*)ldsA1 : (const char*)ldsA0;
            f32x4 acc = (f32x4)(0.f);
#pragma unroll
            for (int kk = 0; kk < 16; ++kk) {
                const int ad = ((lo << 10) + kk * 64 + hi * 16) ^ ((lo & 15) << 4);
                bf16x8 a1 = *(const bf16x8*)(a1base + ad);
                bf16x8 a2 = *(const bf16x8*)(a2base + ad);
                bf16x8 wxf = *(const bf16x8*)(bxp + kk * 32);
                bf16x8 whf = *(const bf16x8*)(bwp + kk * 32);
                acc = __builtin_amdgcn_mfma_f32_16x16x32_bf16(a1, wxf, acc, 0, 0, 0);
                acc = __builtin_amdgcn_mfma_f32_16x16x32_bf16(a2, whf, acc, 0, 0, 0);
            }
            // C/D layout: col = lane&15, row = (lane>>4)*4 + r
#pragma unroll
            for (int r = 0; r < 4; ++r)
                lds_g[lgrp][g][hi * 4 + r][ch * 16 + lo] = acc[r];
        }
        __syncthreads();                   // bar2: gates ready (MFMA + LDS reads done)

        // ---- gates: threads 0..511 (256 per layer), 2 cells each ----
        if (tid < 512 && (glayer ? act1 : act0)) {
            const int t = glayer ? t1 : t0;
            f32x2 gi = *(const f32x2*)&lds_g[glayer][0][grow][cp] + bias2[0];
            f32x2 gf = *(const f32x2*)&lds_g[glayer][1][grow][cp] + bias2[1];
            f32x2 gg = *(const f32x2*)&lds_g[glayer][2][grow][cp] + bias2[2];
            f32x2 go = *(const f32x2*)&lds_g[glayer][3][grow][cp] + bias2[3];
            f32x2 cn, hn;
#pragma unroll
            for (int q = 0; q < 2; ++q) {
                float si = 1.f / (1.f + __expf(-gi[q]));
                float sf = 1.f / (1.f + __expf(-gf[q]));
                float so = 1.f / (1.f + __expf(-go[q]));
                float tg = tanhf(gg[q]);
                cn[q] = sf * creg[q] + si * tg;
                hn[q] = so * tanhf(cn[q]);
            }
            creg = cn;

            unsigned hp = (unsigned)f32_to_bf16(hn[0])
                        | ((unsigned)f32_to_bf16(hn[1]) << 16);
            u64 rec = (u64)hp | ((u64)(unsigned)(t + 1) << 32);
            u64* hw = (glayer ? h1T : h0T)
                    + (size_t)(t & 7) * BRPR
                    + (size_t)(quad * QR + grow) * RPR + ((j0 + cp) >> 1);
            __hip_atomic_store(hw, rec, __ATOMIC_RELAXED,
                               __HIP_MEMORY_SCOPE_AGENT);

            // out / finals (plain stores, off the handshake path)
            const int hoff = (quad * QR + grow) * HID + j0 + cp;
            if (glayer == 1)
                *(f32x2*)&out[(size_t)t * BH + hoff] = hn;
            if (t == TSEQ - 1) {
                size_t base = (size_t)TSEQ * BH + (size_t)glayer * BH + hoff;
                *(f32x2*)&out[base] = hn;                       // h_fin
                *(f32x2*)&out[base + 2 * (size_t)BH] = cn;      // c_fin
            }
        }
        // no trailing barrier: next stage's LDS writes are gated by the retry
        // loops (tag s+1 needs THIS stage's publishes, which follow bar2)
    }
}

extern "C" void kernel_launch(void* const* d_in, const int* in_sizes, int n_in,
                              void* d_out, int out_size, void* d_ws, size_t ws_size,
                              hipStream_t stream) {
    const float* x  = (const float*)d_in[0];
    const float* Wh = (const float*)d_in[1];
    const float* Wx = (const float*)d_in[2];
    const float* bh = (const float*)d_in[3];
    float* out = (float*)d_out;

    char* ws = (char*)d_ws;
    // layout: WT 8MB | xq 32MB | h0T 1MB | h1T 1MB   (~42MB total)
    ushort* WT = (ushort*)ws;
    ushort* xq = (ushort*)(ws + ((size_t)8 << 20));
    char* state = ws + ((size_t)8 << 20) + ((size_t)32 << 20);
    u64* h0T = (u64*)state;                                // [8][64][256] u64
    u64* h1T = h0T + (size_t)DEPTH * BRPR;
    size_t clear_bytes = (size_t)2 * DEPTH * BRPR * sizeof(u64);

    hipMemsetAsync(state, 0, clear_bytes, stream);  // zero all tags
    convert_x<<<2048, 256, 0, stream>>>(x, xq);
    transpose_w<<<1024, 256, 0, stream>>>(Wh, Wx, WT);
    lstm_persistent<<<64, 1024, 0, stream>>>(WT, xq, bh, h0T, h1T, out);
}

// Round 17
// 1828.983 us; speedup vs baseline: 4.7504x; 4.7504x over previous
//
#include <hip/hip_runtime.h>
#include <hip/hip_bf16.h>

// LSTM: T=512, B=64, H=512, L=2.  inputs: x[T,B,H] f32, Wh[L,H,4H], Wx[L,H,4H], bh[L,4H]
// out = concat(out[T,B,H], h_fin[L,B,H], c_fin[L,B,H]) f32.
//
// R17 = EXACT R13 restore (session best: 1832us). Tagged 8B h records
// [2 bf16 | tag=t+1] via relaxed sc1 atomics; data IS the flag; consumers
// retry-load until tags match; 128 WGs = 2 layers x 4 quads x 16 strips x
// 1024 thr; (row&15) LDS swizzle; L1 skew t=s-1; L0 ring-throttle via L1
// progress flag (slack 6). R14 (batched retry), R15 (split retry), R16
// (layer fusion) all regressed - the serialized per-pair retry cadence is
// the best discovered operating point for this latency-bound regime.

#define TSEQ 512
#define BATCH 64
#define HID 512
#define H4 2048
#define BH (BATCH * HID)
#define DEPTH 8
#define QR 16            // batch rows per quad
#define NSTRIP 16        // strips per (layer,quad); 32 cols each
#define RPR 256          // records per row (HID/2)

typedef short bf16x8 __attribute__((ext_vector_type(8)));
typedef float f32x4 __attribute__((ext_vector_type(4)));
typedef float f32x2 __attribute__((ext_vector_type(2)));
typedef unsigned long long u64;
typedef u64 u64x2 __attribute__((ext_vector_type(2)));

__device__ __forceinline__ ushort f32_to_bf16(float f) {
    unsigned u = __builtin_bit_cast(unsigned, f);
    u += 0x7FFFu + ((u >> 16) & 1u);   // round-to-nearest-even
    return (ushort)(u >> 16);
}

// retry-load 4 tagged records (32B) until all tags == tag; returns 8 bf16
__device__ __forceinline__ bf16x8 load_tagged(const u64* p, unsigned tag) {
    u64x2 a, b;
    for (;;) {
        asm volatile("global_load_dwordx4 %0, %2, off sc1\n\t"
                     "global_load_dwordx4 %1, %3, off sc1\n\t"
                     "s_waitcnt vmcnt(0)"
                     : "=&v"(a), "=&v"(b) : "v"(p), "v"(p + 2) : "memory");
        if ((unsigned)(a.x >> 32) == tag && (unsigned)(a.y >> 32) == tag &&
            (unsigned)(b.x >> 32) == tag && (unsigned)(b.y >> 32) == tag) break;
        __builtin_amdgcn_s_sleep(1);
    }
    union { unsigned u[4]; bf16x8 v; } r;
    r.u[0] = (unsigned)a.x; r.u[1] = (unsigned)a.y;
    r.u[2] = (unsigned)b.x; r.u[3] = (unsigned)b.y;
    return r.v;
}

// ---- convert x f32 -> bf16 (vectorized) ----
__global__ __launch_bounds__(256) void convert_x(const float* __restrict__ x,
                                                 ushort* __restrict__ xq) {
    const int n4 = (TSEQ * BATCH * HID) / 4;
    int stride = gridDim.x * blockDim.x;
    for (int i = blockIdx.x * blockDim.x + threadIdx.x; i < n4; i += stride) {
        float4 v = ((const float4*)x)[i];
        ushort4 o;
        o.x = f32_to_bf16(v.x);
        o.y = f32_to_bf16(v.y);
        o.z = f32_to_bf16(v.z);
        o.w = f32_to_bf16(v.w);
        ((ushort4*)xq)[i] = o;
    }
}

// ---- transpose+convert weights: WT[m][n][k] = W[k][n], m: 0=Wx0 1=Wh0 2=Wx1 3=Wh1 ----
__global__ __launch_bounds__(256) void transpose_w(const float* __restrict__ Wh,
                                                   const float* __restrict__ Wx,
                                                   ushort* __restrict__ WT) {
    int bid = blockIdx.x;            // 4 * 8 * 32 = 1024 blocks
    int m  = bid >> 8;               // 0..3
    int kt = (bid >> 5) & 7;         // k tile (64)
    int nt = bid & 31;               // n tile (64)
    const float* src = ((m & 1) ? Wh : Wx) + (size_t)(m >> 1) * (HID * H4);

    __shared__ float tile[64][65];
    int c  = threadIdx.x & 63;
    int r0 = (threadIdx.x >> 6) * 16;
    for (int i = 0; i < 16; ++i) {
        int r = r0 + i;
        tile[r][c] = src[(size_t)(kt * 64 + r) * H4 + nt * 64 + c];
    }
    __syncthreads();
    int k  = threadIdx.x & 63;
    int n0 = (threadIdx.x >> 6) * 16;
    for (int i = 0; i < 16; ++i) {
        int n = n0 + i;
        WT[(size_t)m * (H4 * HID) + (size_t)(nt * 64 + n) * HID + kt * 64 + k] =
            f32_to_bf16(tile[k][n]);
    }
}

// ---- persistent LSTM kernel: 128 WGs x 1024 threads ----
__global__ __launch_bounds__(1024, 4) void lstm_persistent(
    const ushort* __restrict__ WT,   // [4][2048][512] bf16 (N-major, K contiguous)
    const ushort* __restrict__ xq,   // [512][64][512] bf16
    const float*  __restrict__ bh,   // [2][2048]
    u64*   __restrict__ h0T,         // [DEPTH][64][256] tagged records
    u64*   __restrict__ h1T,         // [DEPTH][64][256]
    float* __restrict__ out,         // d_out
    int*   __restrict__ f1prog)      // [4][16] L1 progress (throttle), zeroed
{
    const int wg    = blockIdx.x;        // 0..127
    const int layer = wg >> 6;
    const int quad  = (wg >> 4) & 3;
    const int strip = wg & 15;           // 32-column strip
    const int j0    = strip * 32;
    const int tid   = threadIdx.x;
    const int wave  = tid >> 6;          // 0..15
    const int lane  = tid & 63;
    const int g     = wave & 3;          // gate
    const int ch    = (wave >> 2) & 1;   // col-tile half (16 cols)
    const int kh    = wave >> 3;         // K half (0..1)
    const int lo    = lane & 15;
    const int hi    = lane >> 4;

    int* myprog = &f1prog[quad * NSTRIP + strip];   // only L1 publishes

    // weight fragment base pointers (gemm_bt layout, k contiguous-8/lane)
    const ushort* bx = WT + (size_t)(layer * 2 + 0) * (H4 * HID)
                     + (size_t)(g * 512 + j0 + ch * 16 + lo) * HID + kh * 256 + hi * 8;
    const ushort* bw = WT + (size_t)(layer * 2 + 1) * (H4 * HID)
                     + (size_t)(g * 512 + j0 + ch * 16 + lo) * HID + kh * 256 + hi * 8;
    bf16x8 wx[8], wh[8];
#pragma unroll
    for (int kk = 0; kk < 8; ++kk) {
        wx[kk] = *(const bf16x8*)(bx + kk * 32);
        wh[kk] = *(const bf16x8*)(bw + kk * 32);
    }
#pragma unroll
    for (int kk = 0; kk < 8; ++kk) {
        asm volatile("" : "+v"(wx[kk]));
        asm volatile("" : "+v"(wh[kk]));
    }

    // gate-phase mapping (threads 0..255): row = tid>>4 (0..15), cols cp,cp+1 (0..31)
    const int grow = tid >> 4;
    const int cp   = (tid & 15) * 2;
    f32x2 bias2[4];
#pragma unroll
    for (int gg = 0; gg < 4; ++gg)
        bias2[gg] = *(const f32x2*)&bh[layer * H4 + gg * 512 + j0 + cp];
    f32x2 creg = (f32x2)(0.f);

    __shared__ __align__(16) ushort ldsA[2][QR * HID];      // 32 KB: A1, A2 tiles
    __shared__ __align__(16) float  lds_g[4][2][QR][34];    // padded (32+2)

    // staging: 1024 threads, 8 bf16 per matrix: row = tid>>6, kba = tid&63
    const int row  = tid >> 6;             // 0..15
    const int kba  = tid & 63;
    const int goff  = (quad * QR + row) * HID + kba * 8;               // bf16 elems
    const int roff  = (quad * QR + row) * RPR + kba * 4;               // records
    const int laddr = ((row << 10) + (kba << 4)) ^ ((row & 15) << 4);
    const bf16x8 zero8 = {0, 0, 0, 0, 0, 0, 0, 0};

    for (int s = 0; s <= TSEQ; ++s) {
        const int t = s - layer;
        const bool active = (t >= 0 && t < TSEQ);

        if (active) {
            bf16x8 v0, v1;
            if (layer == 0) {
                // xq static: plain cached load (L2-hot)
                v0 = *(const bf16x8*)(xq + (size_t)t * BH + goff);
                // ring-overwrite throttle: L1 must be past s-6 (slack; rarely spins)
                if (s >= 6 && tid < NSTRIP) {
                    const int* f = &f1prog[quad * NSTRIP + tid];
                    while (__hip_atomic_load(f, __ATOMIC_RELAXED,
                                             __HIP_MEMORY_SCOPE_AGENT) < s - 6)
                        __builtin_amdgcn_s_sleep(1);
                }
                // self-recurrence h0[t-1]: tagged retry-load (tag = t)
                v1 = (t == 0) ? zero8
                              : load_tagged(h0T + (size_t)((t - 1) & 7) * (BATCH * RPR)
                                            + roff, (unsigned)t);
            } else {
                // h0[t]: tag t+1 (one stage of pipeline slack via skew)
                v0 = load_tagged(h0T + (size_t)(t & 7) * (BATCH * RPR) + roff,
                                 (unsigned)(t + 1));
                // self-recurrence h1[t-1]: tag t
                v1 = (t == 0) ? zero8
                              : load_tagged(h1T + (size_t)((t - 1) & 7) * (BATCH * RPR)
                                            + roff, (unsigned)t);
            }
            __builtin_amdgcn_sched_barrier(0);
            *(bf16x8*)((char*)&ldsA[0][0] + laddr) = v0;
            *(bf16x8*)((char*)&ldsA[1][0] + laddr) = v1;
            __syncthreads();                         // bar1: tiles staged

            // L1 progress publish (throttle only; no drain needed)
            if (layer == 1 && tid == 0)
                __hip_atomic_store(myprog, s, __ATOMIC_RELAXED,
                                   __HIP_MEMORY_SCOPE_AGENT);

            // MFMA: wave (g, ch, kh) computes 16x16 tile (cols ch*16), K-half kh
            f32x4 acc = (f32x4)(0.f);
#pragma unroll
            for (int kk = 0; kk < 8; ++kk) {
                const int kb2 = kh * 512 + kk * 64 + hi * 16;        // byte offset in row
                const int ad  = ((lo << 10) + kb2) ^ ((lo & 15) << 4);
                bf16x8 a1 = *(const bf16x8*)((char*)&ldsA[0][0] + ad);
                bf16x8 a2 = *(const bf16x8*)((char*)&ldsA[1][0] + ad);
                acc = __builtin_amdgcn_mfma_f32_16x16x32_bf16(a1, wx[kk], acc, 0, 0, 0);
                acc = __builtin_amdgcn_mfma_f32_16x16x32_bf16(a2, wh[kk], acc, 0, 0, 0);
            }
            // C/D layout: col = lane&15, row = (lane>>4)*4 + r
#pragma unroll
            for (int r = 0; r < 4; ++r)
                lds_g[g][kh][hi * 4 + r][ch * 16 + lo] = acc[r];
            __syncthreads();                         // bar2: partials ready

            // gates (threads 0..255): 2 cells per thread; publish tagged record
            if (tid < 256) {
                f32x2 gi = *(const f32x2*)&lds_g[0][0][grow][cp]
                         + *(const f32x2*)&lds_g[0][1][grow][cp] + bias2[0];
                f32x2 gf = *(const f32x2*)&lds_g[1][0][grow][cp]
                         + *(const f32x2*)&lds_g[1][1][grow][cp] + bias2[1];
                f32x2 gg = *(const f32x2*)&lds_g[2][0][grow][cp]
                         + *(const f32x2*)&lds_g[2][1][grow][cp] + bias2[2];
                f32x2 go = *(const f32x2*)&lds_g[3][0][grow][cp]
                         + *(const f32x2*)&lds_g[3][1][grow][cp] + bias2[3];
                f32x2 cn, hn;
#pragma unroll
                for (int q = 0; q < 2; ++q) {
                    float si = 1.f / (1.f + __expf(-gi[q]));
                    float sf = 1.f / (1.f + __expf(-gf[q]));
                    float so = 1.f / (1.f + __expf(-go[q]));
                    float tg = tanhf(gg[q]);
                    cn[q] = sf * creg[q] + si * tg;
                    hn[q] = so * tanhf(cn[q]);
                }
                creg = cn;

                unsigned hp = (unsigned)f32_to_bf16(hn[0])
                            | ((unsigned)f32_to_bf16(hn[1]) << 16);
                u64 rec = (u64)hp | ((u64)(unsigned)(t + 1) << 32);
                u64* hw = ((layer == 0) ? h0T : h1T)
                        + (size_t)(t & 7) * (BATCH * RPR)
                        + (size_t)(quad * QR + grow) * RPR + ((j0 + cp) >> 1);
                __hip_atomic_store(hw, rec, __ATOMIC_RELAXED,
                                   __HIP_MEMORY_SCOPE_AGENT);

                // out / finals (plain stores, off the handshake path)
                const int hoff = (quad * QR + grow) * HID + j0 + cp;
                if (layer == 1)
                    *(f32x2*)&out[(size_t)t * BH + hoff] = hn;
                if (t == TSEQ - 1) {
                    size_t base = (size_t)TSEQ * BH + (size_t)layer * BH + hoff;
                    *(f32x2*)&out[base] = hn;                       // h_fin
                    *(f32x2*)&out[base + 2 * (size_t)BH] = cn;      // c_fin
                }
            }
        } else {
            // inactive stage: L1 keeps progress monotone for the throttle
            if (layer == 1 && tid == 0)
                __hip_atomic_store(myprog, s, __ATOMIC_RELAXED,
                                   __HIP_MEMORY_SCOPE_AGENT);
            __syncthreads();
        }
    }
}

extern "C" void kernel_launch(void* const* d_in, const int* in_sizes, int n_in,
                              void* d_out, int out_size, void* d_ws, size_t ws_size,
                              hipStream_t stream) {
    const float* x  = (const float*)d_in[0];
    const float* Wh = (const float*)d_in[1];
    const float* Wx = (const float*)d_in[2];
    const float* bh = (const float*)d_in[3];
    float* out = (float*)d_out;

    char* ws = (char*)d_ws;
    // layout: WT 8MB | xq 32MB | h0T 1MB | h1T 1MB | f1prog  (~42MB total)
    ushort* WT = (ushort*)ws;
    ushort* xq = (ushort*)(ws + ((size_t)8 << 20));
    char* state = ws + ((size_t)8 << 20) + ((size_t)32 << 20);
    u64* h0T = (u64*)state;                                // [8][64][256] u64
    u64* h1T = h0T + (size_t)DEPTH * BATCH * RPR;
    int* f1prog = (int*)(h1T + (size_t)DEPTH * BATCH * RPR);   // [4][16]
    size_t clear_bytes = (size_t)2 * DEPTH * BATCH * RPR * sizeof(u64)
                       + 64 * sizeof(int);

    hipMemsetAsync(state, 0, clear_bytes, stream);  // zero tags + progress flags
    convert_x<<<2048, 256, 0, stream>>>(x, xq);
    transpose_w<<<1024, 256, 0, stream>>>(Wh, Wx, WT);
    lstm_persistent<<<128, 1024, 0, stream>>>(WT, xq, bh, h0T, h1T, out, f1prog);
}

// Round 18
// 1649.410 us; speedup vs baseline: 5.2676x; 1.1089x over previous
//
#include <hip/hip_runtime.h>
#include <hip/hip_bf16.h>

// LSTM: T=512, B=64, H=512, L=2.  inputs: x[T,B,H] f32, Wh[L,H,4H], Wx[L,H,4H], bh[L,4H]
// out = concat(out[T,B,H], h_fin[L,B,H], c_fin[L,B,H]) f32.
//
// R18 = R13/R17 (session best 1829us: tagged 8B h records, relaxed sc1, data
// IS the flag, serialized per-pair retries, 128 WGs = 2x4x16 x 1024 thr)
// + two CRITICAL-PATH COMPUTE cuts (no sync/protocol change):
//  (a) MFMA split into two independent 8-deep chains (acc0=Wx, acc1=Wh,
//      summed once) - halves the serially-dependent MFMA latency segment
//  (b) tanh via 1-2/(1+expf(2x)) in gates (libm tanhf ~40-80cy -> ~15cy;
//      4 calls/thread on the critical path)
// Both were only ever tested inside R10's regressing bundle (regressor there
// was the skew); this isolates them on the proven base.

#define TSEQ 512
#define BATCH 64
#define HID 512
#define H4 2048
#define BH (BATCH * HID)
#define DEPTH 8
#define QR 16            // batch rows per quad
#define NSTRIP 16        // strips per (layer,quad); 32 cols each
#define RPR 256          // records per row (HID/2)

typedef short bf16x8 __attribute__((ext_vector_type(8)));
typedef float f32x4 __attribute__((ext_vector_type(4)));
typedef float f32x2 __attribute__((ext_vector_type(2)));
typedef unsigned long long u64;
typedef u64 u64x2 __attribute__((ext_vector_type(2)));

__device__ __forceinline__ ushort f32_to_bf16(float f) {
    unsigned u = __builtin_bit_cast(unsigned, f);
    u += 0x7FFFu + ((u >> 16) & 1u);   // round-to-nearest-even
    return (ushort)(u >> 16);
}

__device__ __forceinline__ float tanh_fast(float x) {
    return 1.f - 2.f / (1.f + __expf(2.f * x));   // exact at +-inf, ~1e-7 rel err
}

// retry-load 4 tagged records (32B) until all tags == tag; returns 8 bf16
__device__ __forceinline__ bf16x8 load_tagged(const u64* p, unsigned tag) {
    u64x2 a, b;
    for (;;) {
        asm volatile("global_load_dwordx4 %0, %2, off sc1\n\t"
                     "global_load_dwordx4 %1, %3, off sc1\n\t"
                     "s_waitcnt vmcnt(0)"
                     : "=&v"(a), "=&v"(b) : "v"(p), "v"(p + 2) : "memory");
        if ((unsigned)(a.x >> 32) == tag && (unsigned)(a.y >> 32) == tag &&
            (unsigned)(b.x >> 32) == tag && (unsigned)(b.y >> 32) == tag) break;
        __builtin_amdgcn_s_sleep(1);
    }
    union { unsigned u[4]; bf16x8 v; } r;
    r.u[0] = (unsigned)a.x; r.u[1] = (unsigned)a.y;
    r.u[2] = (unsigned)b.x; r.u[3] = (unsigned)b.y;
    return r.v;
}

// ---- convert x f32 -> bf16 (vectorized) ----
__global__ __launch_bounds__(256) void convert_x(const float* __restrict__ x,
                                                 ushort* __restrict__ xq) {
    const int n4 = (TSEQ * BATCH * HID) / 4;
    int stride = gridDim.x * blockDim.x;
    for (int i = blockIdx.x * blockDim.x + threadIdx.x; i < n4; i += stride) {
        float4 v = ((const float4*)x)[i];
        ushort4 o;
        o.x = f32_to_bf16(v.x);
        o.y = f32_to_bf16(v.y);
        o.z = f32_to_bf16(v.z);
        o.w = f32_to_bf16(v.w);
        ((ushort4*)xq)[i] = o;
    }
}

// ---- transpose+convert weights: WT[m][n][k] = W[k][n], m: 0=Wx0 1=Wh0 2=Wx1 3=Wh1 ----
__global__ __launch_bounds__(256) void transpose_w(const float* __restrict__ Wh,
                                                   const float* __restrict__ Wx,
                                                   ushort* __restrict__ WT) {
    int bid = blockIdx.x;            // 4 * 8 * 32 = 1024 blocks
    int m  = bid >> 8;               // 0..3
    int kt = (bid >> 5) & 7;         // k tile (64)
    int nt = bid & 31;               // n tile (64)
    const float* src = ((m & 1) ? Wh : Wx) + (size_t)(m >> 1) * (HID * H4);

    __shared__ float tile[64][65];
    int c  = threadIdx.x & 63;
    int r0 = (threadIdx.x >> 6) * 16;
    for (int i = 0; i < 16; ++i) {
        int r = r0 + i;
        tile[r][c] = src[(size_t)(kt * 64 + r) * H4 + nt * 64 + c];
    }
    __syncthreads();
    int k  = threadIdx.x & 63;
    int n0 = (threadIdx.x >> 6) * 16;
    for (int i = 0; i < 16; ++i) {
        int n = n0 + i;
        WT[(size_t)m * (H4 * HID) + (size_t)(nt * 64 + n) * HID + kt * 64 + k] =
            f32_to_bf16(tile[k][n]);
    }
}

// ---- persistent LSTM kernel: 128 WGs x 1024 threads ----
__global__ __launch_bounds__(1024, 4) void lstm_persistent(
    const ushort* __restrict__ WT,   // [4][2048][512] bf16 (N-major, K contiguous)
    const ushort* __restrict__ xq,   // [512][64][512] bf16
    const float*  __restrict__ bh,   // [2][2048]
    u64*   __restrict__ h0T,         // [DEPTH][64][256] tagged records
    u64*   __restrict__ h1T,         // [DEPTH][64][256]
    float* __restrict__ out,         // d_out
    int*   __restrict__ f1prog)      // [4][16] L1 progress (throttle), zeroed
{
    const int wg    = blockIdx.x;        // 0..127
    const int layer = wg >> 6;
    const int quad  = (wg >> 4) & 3;
    const int strip = wg & 15;           // 32-column strip
    const int j0    = strip * 32;
    const int tid   = threadIdx.x;
    const int wave  = tid >> 6;          // 0..15
    const int lane  = tid & 63;
    const int g     = wave & 3;          // gate
    const int ch    = (wave >> 2) & 1;   // col-tile half (16 cols)
    const int kh    = wave >> 3;         // K half (0..1)
    const int lo    = lane & 15;
    const int hi    = lane >> 4;

    int* myprog = &f1prog[quad * NSTRIP + strip];   // only L1 publishes

    // weight fragment base pointers (gemm_bt layout, k contiguous-8/lane)
    const ushort* bx = WT + (size_t)(layer * 2 + 0) * (H4 * HID)
                     + (size_t)(g * 512 + j0 + ch * 16 + lo) * HID + kh * 256 + hi * 8;
    const ushort* bw = WT + (size_t)(layer * 2 + 1) * (H4 * HID)
                     + (size_t)(g * 512 + j0 + ch * 16 + lo) * HID + kh * 256 + hi * 8;
    bf16x8 wx[8], wh[8];
#pragma unroll
    for (int kk = 0; kk < 8; ++kk) {
        wx[kk] = *(const bf16x8*)(bx + kk * 32);
        wh[kk] = *(const bf16x8*)(bw + kk * 32);
    }
#pragma unroll
    for (int kk = 0; kk < 8; ++kk) {
        asm volatile("" : "+v"(wx[kk]));
        asm volatile("" : "+v"(wh[kk]));
    }

    // gate-phase mapping (threads 0..255): row = tid>>4 (0..15), cols cp,cp+1 (0..31)
    const int grow = tid >> 4;
    const int cp   = (tid & 15) * 2;
    f32x2 bias2[4];
#pragma unroll
    for (int gg = 0; gg < 4; ++gg)
        bias2[gg] = *(const f32x2*)&bh[layer * H4 + gg * 512 + j0 + cp];
    f32x2 creg = (f32x2)(0.f);

    __shared__ __align__(16) ushort ldsA[2][QR * HID];      // 32 KB: A1, A2 tiles
    __shared__ __align__(16) float  lds_g[4][2][QR][34];    // padded (32+2)

    // staging: 1024 threads, 8 bf16 per matrix: row = tid>>6, kba = tid&63
    const int row  = tid >> 6;             // 0..15
    const int kba  = tid & 63;
    const int goff  = (quad * QR + row) * HID + kba * 8;               // bf16 elems
    const int roff  = (quad * QR + row) * RPR + kba * 4;               // records
    const int laddr = ((row << 10) + (kba << 4)) ^ ((row & 15) << 4);
    const bf16x8 zero8 = {0, 0, 0, 0, 0, 0, 0, 0};

    for (int s = 0; s <= TSEQ; ++s) {
        const int t = s - layer;
        const bool active = (t >= 0 && t < TSEQ);

        if (active) {
            bf16x8 v0, v1;
            if (layer == 0) {
                // xq static: plain cached load (L2-hot)
                v0 = *(const bf16x8*)(xq + (size_t)t * BH + goff);
                // ring-overwrite throttle: L1 must be past s-6 (slack; rarely spins)
                if (s >= 6 && tid < NSTRIP) {
                    const int* f = &f1prog[quad * NSTRIP + tid];
                    while (__hip_atomic_load(f, __ATOMIC_RELAXED,
                                             __HIP_MEMORY_SCOPE_AGENT) < s - 6)
                        __builtin_amdgcn_s_sleep(1);
                }
                // self-recurrence h0[t-1]: tagged retry-load (tag = t)
                v1 = (t == 0) ? zero8
                              : load_tagged(h0T + (size_t)((t - 1) & 7) * (BATCH * RPR)
                                            + roff, (unsigned)t);
            } else {
                // h0[t]: tag t+1 (one stage of pipeline slack via skew)
                v0 = load_tagged(h0T + (size_t)(t & 7) * (BATCH * RPR) + roff,
                                 (unsigned)(t + 1));
                // self-recurrence h1[t-1]: tag t
                v1 = (t == 0) ? zero8
                              : load_tagged(h1T + (size_t)((t - 1) & 7) * (BATCH * RPR)
                                            + roff, (unsigned)t);
            }
            __builtin_amdgcn_sched_barrier(0);
            *(bf16x8*)((char*)&ldsA[0][0] + laddr) = v0;
            *(bf16x8*)((char*)&ldsA[1][0] + laddr) = v1;
            __syncthreads();                         // bar1: tiles staged

            // L1 progress publish (throttle only; no drain needed)
            if (layer == 1 && tid == 0)
                __hip_atomic_store(myprog, s, __ATOMIC_RELAXED,
                                   __HIP_MEMORY_SCOPE_AGENT);

            // MFMA: wave (g, ch, kh); TWO independent 8-deep chains
            f32x4 acc0 = (f32x4)(0.f), acc1 = (f32x4)(0.f);
#pragma unroll
            for (int kk = 0; kk < 8; ++kk) {
                const int kb2 = kh * 512 + kk * 64 + hi * 16;        // byte offset in row
                const int ad  = ((lo << 10) + kb2) ^ ((lo & 15) << 4);
                bf16x8 a1 = *(const bf16x8*)((char*)&ldsA[0][0] + ad);
                bf16x8 a2 = *(const bf16x8*)((char*)&ldsA[1][0] + ad);
                acc0 = __builtin_amdgcn_mfma_f32_16x16x32_bf16(a1, wx[kk], acc0, 0, 0, 0);
                acc1 = __builtin_amdgcn_mfma_f32_16x16x32_bf16(a2, wh[kk], acc1, 0, 0, 0);
            }
            f32x4 acc = acc0 + acc1;
            // C/D layout: col = lane&15, row = (lane>>4)*4 + r
#pragma unroll
            for (int r = 0; r < 4; ++r)
                lds_g[g][kh][hi * 4 + r][ch * 16 + lo] = acc[r];
            __syncthreads();                         // bar2: partials ready

            // gates (threads 0..255): 2 cells per thread; publish tagged record
            if (tid < 256) {
                f32x2 gi = *(const f32x2*)&lds_g[0][0][grow][cp]
                         + *(const f32x2*)&lds_g[0][1][grow][cp] + bias2[0];
                f32x2 gf = *(const f32x2*)&lds_g[1][0][grow][cp]
                         + *(const f32x2*)&lds_g[1][1][grow][cp] + bias2[1];
                f32x2 gg = *(const f32x2*)&lds_g[2][0][grow][cp]
                         + *(const f32x2*)&lds_g[2][1][grow][cp] + bias2[2];
                f32x2 go = *(const f32x2*)&lds_g[3][0][grow][cp]
                         + *(const f32x2*)&lds_g[3][1][grow][cp] + bias2[3];
                f32x2 cn, hn;
#pragma unroll
                for (int q = 0; q < 2; ++q) {
                    float si = 1.f / (1.f + __expf(-gi[q]));
                    float sf = 1.f / (1.f + __expf(-gf[q]));
                    float so = 1.f / (1.f + __expf(-go[q]));
                    float tg = tanh_fast(gg[q]);
                    cn[q] = sf * creg[q] + si * tg;
                    hn[q] = so * tanh_fast(cn[q]);
                }
                creg = cn;

                unsigned hp = (unsigned)f32_to_bf16(hn[0])
                            | ((unsigned)f32_to_bf16(hn[1]) << 16);
                u64 rec = (u64)hp | ((u64)(unsigned)(t + 1) << 32);
                u64* hw = ((layer == 0) ? h0T : h1T)
                        + (size_t)(t & 7) * (BATCH * RPR)
                        + (size_t)(quad * QR + grow) * RPR + ((j0 + cp) >> 1);
                __hip_atomic_store(hw, rec, __ATOMIC_RELAXED,
                                   __HIP_MEMORY_SCOPE_AGENT);

                // out / finals (plain stores, off the handshake path)
                const int hoff = (quad * QR + grow) * HID + j0 + cp;
                if (layer == 1)
                    *(f32x2*)&out[(size_t)t * BH + hoff] = hn;
                if (t == TSEQ - 1) {
                    size_t base = (size_t)TSEQ * BH + (size_t)layer * BH + hoff;
                    *(f32x2*)&out[base] = hn;                       // h_fin
                    *(f32x2*)&out[base + 2 * (size_t)BH] = cn;      // c_fin
                }
            }
        } else {
            // inactive stage: L1 keeps progress monotone for the throttle
            if (layer == 1 && tid == 0)
                __hip_atomic_store(myprog, s, __ATOMIC_RELAXED,
                                   __HIP_MEMORY_SCOPE_AGENT);
            __syncthreads();
        }
    }
}

extern "C" void kernel_launch(void* const* d_in, const int* in_sizes, int n_in,
                              void* d_out, int out_size, void* d_ws, size_t ws_size,
                              hipStream_t stream) {
    const float* x  = (const float*)d_in[0];
    const float* Wh = (const float*)d_in[1];
    const float* Wx = (const float*)d_in[2];
    const float* bh = (const float*)d_in[3];
    float* out = (float*)d_out;

    char* ws = (char*)d_ws;
    // layout: WT 8MB | xq 32MB | h0T 1MB | h1T 1MB | f1prog  (~42MB total)
    ushort* WT = (ushort*)ws;
    ushort* xq = (ushort*)(ws + ((size_t)8 << 20));
    char* state = ws + ((size_t)8 << 20) + ((size_t)32 << 20);
    u64* h0T = (u64*)state;                                // [8][64][256] u64
    u64* h1T = h0T + (size_t)DEPTH * BATCH * RPR;
    int* f1prog = (int*)(h1T + (size_t)DEPTH * BATCH * RPR);   // [4][16]
    size_t clear_bytes = (size_t)2 * DEPTH * BATCH * RPR * sizeof(u64)
                       + 64 * sizeof(int);

    hipMemsetAsync(state, 0, clear_bytes, stream);  // zero tags + progress flags
    convert_x<<<2048, 256, 0, stream>>>(x, xq);
    transpose_w<<<1024, 256, 0, stream>>>(Wh, Wx, WT);
    lstm_persistent<<<128, 1024, 0, stream>>>(WT, xq, bh, h0T, h1T, out, f1prog);
}